// Round 7
// baseline (19649.541 us; speedup 1.0000x reference)
//
#include <hip/hip_runtime.h>
#include <hip/hip_bf16.h>

typedef unsigned long long ull;
typedef unsigned int uint;
typedef float f32x4 __attribute__((ext_vector_type(4)));   // clang vectors: valid for nontemporal builtins
typedef uint  u32x2 __attribute__((ext_vector_type(2)));

#define TSTEPS 512
#define BATCH  128
#define DIM    512
#define HDIM   512
#define ODIM   256
#define N3     1536

// ---- ws layout (float offsets) ----
#define OFF_BAR  0
#define OFF_XT   512       // xT  [256][128]
#define OFF_ST   33280     // sT  [512][128]
#define OFF_ZT   98816     // zT  [512][128]
#define OFF_RST  164352    // rsT [512][128]
#define OFF_PST  229888    // psT [512][128]
#define OFF_SUT  295424    // suT [1024][128]
#define OFF_WT   426496    // Wt   [1536][256]
#define OFF_UT1  819712    // Ut1  [1024][512]
#define OFF_UST  1344000   // Ust  [512][512]
#define OFF_WXOT 1606144   // Wxot [256][512]
#define OFF_HV   1737216   // bf16 [512][1536][128]

// ---- dynamic LDS (float offsets) ----
// stage: [8 rq][k][4 rows], rq-stride 2052 (pad 4) -> b128 reads/writes where
//        each aligned 8-lane group starts at bank 4*rq -> full 32-bank coverage.
// weights: k-blocks padded +4 floats per K-split slice so the 8 broadcast
//        addresses of a wave occupy 8 disjoint 4-bank windows.
#define SSTRIDE  2052
#define WP1_OFF  16416     // [24][288]  (256 + 8 pads of 4 per 32-k block)
#define WP2_OFF  23328     // [8][544]   (512 + 8 pads of 4 per 64-k block)
#define WP3U_OFF 27680     // [16][544]
#define WP3X_OFF 36384     // [4][544]
#define LDSF_TOTAL 38560
#define LDS_BYTES  (LDSF_TOTAL * 4)   // 154240 <= 160K

union U64 { ull u; float2 f; double d; };

__device__ __forceinline__ float sigmoid_(float a) {
  return 1.0f / (1.0f + __expf(-a));
}
__device__ __forceinline__ float tanh_(float a) {
  a = fminf(fmaxf(a, -30.0f), 30.0f);
  float e = __expf(2.0f * a);
  return (e - 1.0f) / (e + 1.0f);
}

// LLC-coherent state accessors (bypass incoherent per-XCD L2, no fences).
__device__ __forceinline__ float2 ld2(const float* p) {
  U64 u; u.u = __hip_atomic_load((ull*)p, __ATOMIC_RELAXED, __HIP_MEMORY_SCOPE_AGENT);
  return u.f;
}
__device__ __forceinline__ void st2(float* p, float2 v) {
  U64 u; u.f = v;
  __hip_atomic_store((ull*)p, u.u, __ATOMIC_RELAXED, __HIP_MEMORY_SCOPE_AGENT);
}
__device__ __forceinline__ float4 ld4(const float* p) {
  float2 a = ld2(p), b = ld2(p + 2);
  return make_float4(a.x, a.y, b.x, b.y);
}
__device__ __forceinline__ void st4(float* p, float4 v) {
  st2(p, make_float2(v.x, v.y));
  st2(p + 2, make_float2(v.z, v.w));
}

__device__ __forceinline__ float bflo(uint u) { return __uint_as_float(u << 16); }
__device__ __forceinline__ float bfhi(uint u) { return __uint_as_float(u & 0xffff0000u); }
// 4 bf16 (4 consecutive batch rows) nontemporal
__device__ __forceinline__ float4 ldhv4(const __hip_bfloat16* p) {
  u32x2 u = __builtin_nontemporal_load((const u32x2*)p);
  return make_float4(bflo(u.x), bfhi(u.x), bflo(u.y), bfhi(u.y));
}
__device__ __forceinline__ void stnt4(float* p, float4 v) {
  f32x4 w = {v.x, v.y, v.z, v.w};
  __builtin_nontemporal_store(w, (f32x4*)p);
}

#define FMA4(A, S, W) \
  A.x = fmaf(S.x, W, A.x); A.y = fmaf(S.y, W, A.y); \
  A.z = fmaf(S.z, W, A.z); A.w = fmaf(S.w, W, A.w)

// ---- one-time weight transposes into ws ----
__global__ void prep_kernel(const float* __restrict__ W, const float* __restrict__ U,
                            const float* __restrict__ Wx, float* __restrict__ ws) {
  int i = blockIdx.x * 256 + threadIdx.x;
  if (i < 393216) {                       // Wt[c][k] = W[k][c]
    int c = i >> 8, k = i & 255;
    ws[OFF_WT + i] = W[(size_t)k * N3 + c];
  } else if (i < 917504) {                // Ut1[c][k] = U[k][c], c<1024
    int j = i - 393216; int c = j >> 9, k = j & 511;
    ws[OFF_UT1 + j] = U[(size_t)k * N3 + c];
  } else if (i < 1179648) {               // Ust[c][k] = U[k][1024+c]
    int j = i - 917504; int c = j >> 9, k = j & 511;
    ws[OFF_UST + j] = U[(size_t)k * N3 + 1024 + c];
  } else if (i < 1310720) {               // Wxot[c][k] = W_x[k][c], c<256
    int j = i - 1179648; int c = j >> 9, k = j & 511;
    ws[OFF_WXOT + j] = Wx[(size_t)k * 768 + c];
  }
}

// ---- state init ----
__global__ void init_kernel(const float* __restrict__ H, float* __restrict__ ws) {
  int i = blockIdx.x * 256 + threadIdx.x;   // grid 512 -> 131072
  if (i < 512) ((unsigned*)ws)[OFF_BAR + i] = 0u;
  if (i < 65536) ws[OFF_ST + i] = 0.0f;
  if (i < 131072) ws[OFF_SUT + i] = 0.0f;
  if (i < 32768) {
    int c = i >> 7, b = i & 127;
    const float* hrow = H + ((size_t)b * TSTEPS + (TSTEPS - 1)) * DIM;
    ws[OFF_XT + i] = hrow[c] + hrow[c + ODIM];
  }
}

// ---- hv precompute, transposed bf16 store: hvT[t][c][b] ----
__global__ void hv_kernel(const float* __restrict__ H,
                          const float* __restrict__ Vr,
                          const float* __restrict__ Vz,
                          const float* __restrict__ Vs,
                          __hip_bfloat16* __restrict__ hvT) {
  __shared__ float tile[64 * 33];
  int c  = threadIdx.x & 63;
  int q  = threadIdx.x >> 6;
  int i0 = blockIdx.x * 32;
  int l  = i0 >> 7;
  int b0 = i0 & 127;
  int n0 = blockIdx.y * 64;
  int seg = n0 >> 9;
  int jj  = (n0 & 511) + c;
  const float* V = (seg == 0) ? Vr : ((seg == 1) ? Vz : Vs);

  const float* Arow[8];
  #pragma unroll
  for (int rr = 0; rr < 8; ++rr) {
    int b = b0 + q + rr * 4;
    Arow[rr] = H + ((size_t)b * TSTEPS + (TSTEPS - 1 - l)) * DIM;
  }
  float acc[8];
  #pragma unroll
  for (int rr = 0; rr < 8; ++rr) acc[rr] = 0.0f;

  for (int k = 0; k < DIM; k += 4) {
    float v0 = V[(size_t)(k + 0) * HDIM + jj];
    float v1 = V[(size_t)(k + 1) * HDIM + jj];
    float v2 = V[(size_t)(k + 2) * HDIM + jj];
    float v3 = V[(size_t)(k + 3) * HDIM + jj];
    #pragma unroll
    for (int rr = 0; rr < 8; ++rr) {
      float4 a = *(const float4*)(Arow[rr] + k);
      acc[rr] = fmaf(a.x, v0, acc[rr]);
      acc[rr] = fmaf(a.y, v1, acc[rr]);
      acc[rr] = fmaf(a.z, v2, acc[rr]);
      acc[rr] = fmaf(a.w, v3, acc[rr]);
    }
  }
  #pragma unroll
  for (int rr = 0; rr < 8; ++rr) tile[c * 33 + q + 4 * rr] = acc[rr];
  __syncthreads();
  #pragma unroll
  for (int i = 0; i < 8; ++i) {
    int lin = i * 256 + threadIdx.x;
    int cc = lin >> 5, bb = lin & 31;
    __hip_bfloat16 hb = __float2bfloat16(tile[cc * 33 + bb]);
    __builtin_nontemporal_store(*(unsigned short*)&hb,
        (unsigned short*)(hvT + ((size_t)l * N3 + n0 + cc) * 128 + b0 + bb));
  }
}

// ---- cooperative stage of state [k][128] col-slice into LDS [rq][k][4] ----
// thread: rq = tid&7 (rows 4rq..4rq+3), k0 = tid>>3, k = k0 + 64u.
// Global: 2x ld2 (8B agent) per (rq,k); LDS: one b128 write, bank-clean.
template<int KR>
__device__ __forceinline__ void stageQ(const float* __restrict__ src, int r0,
                                       int tid, float* smem) {
  const int rq = tid & 7;
  const int k0 = tid >> 3;
  constexpr int NU = KR / 64;
  float2 va[NU], vb[NU];
#pragma unroll
  for (int u = 0; u < NU; ++u) {
    const float* g = src + (size_t)(k0 + u * 64) * 128 + r0 + rq * 4;
    va[u] = ld2(g);
    vb[u] = ld2(g + 2);
  }
#pragma unroll
  for (int u = 0; u < NU; ++u) {
    *(float4*)(smem + (size_t)rq * SSTRIDE + (size_t)(k0 + u * 64) * 4) =
        make_float4(va[u].x, va[u].y, vb[u].x, vb[u].y);
  }
}

// ---- NC cols x 4 rows x K-slice dot; state+weights from LDS, all b128 ----
template<int NC, int ITERS>
__device__ __forceinline__ void dotNC(const float* sb, const float* wq, int wstride,
                                      float4* acc) {
  const float4* S = (const float4*)sb;
  const float4* W[NC];
#pragma unroll
  for (int c = 0; c < NC; ++c) W[c] = (const float4*)(wq + c * wstride);
#pragma unroll 4
  for (int i = 0; i < ITERS; ++i) {
    float4 s0 = S[i * 4 + 0], s1 = S[i * 4 + 1];
    float4 s2 = S[i * 4 + 2], s3 = S[i * 4 + 3];
#pragma unroll
    for (int c = 0; c < NC; ++c) {
      float4 w = W[c][i];
      FMA4(acc[c], s0, w.x);
      FMA4(acc[c], s1, w.y);
      FMA4(acc[c], s2, w.z);
      FMA4(acc[c], s3, w.w);
    }
  }
}

// ---- 8-way K-split reduction: partners are lanes ^8,^16,^32 (same wave) ----
template<int NC>
__device__ __forceinline__ void redNC(float4* acc) {
#pragma unroll
  for (int m = 8; m <= 32; m <<= 1) {
#pragma unroll
    for (int c = 0; c < NC; ++c) {
      acc[c].x += __shfl_xor(acc[c].x, m);
      acc[c].y += __shfl_xor(acc[c].y, m);
      acc[c].z += __shfl_xor(acc[c].z, m);
      acc[c].w += __shfl_xor(acc[c].w, m);
    }
  }
}

// ---- flat fence-free quadrant barrier: 8 spread counters, pollers sum all 8
__device__ __forceinline__ void quad_barrier(unsigned* qbar, int lbid, unsigned ep) {
  __syncthreads();
  if (threadIdx.x == 0) {
    asm volatile("s_waitcnt vmcnt(0)" ::: "memory");
    unsigned gslot = (unsigned)(lbid >> 3) * 16u;   // 8 slots, 64B apart
    __hip_atomic_fetch_add(&qbar[gslot], 1u, __ATOMIC_RELAXED, __HIP_MEMORY_SCOPE_AGENT);
    unsigned tgt = ep * 64u;
    for (;;) {
      unsigned s = 0;
      #pragma unroll
      for (int i = 0; i < 8; ++i)
        s += __hip_atomic_load(&qbar[i * 16], __ATOMIC_RELAXED, __HIP_MEMORY_SCOPE_AGENT);
      if (s >= tgt) break;
      __builtin_amdgcn_s_sleep(1);
    }
  }
  __syncthreads();
}

// ---- persistent scan: 256 blocks x 512 threads, 4 independent batch-quadrants.
// Fat threads: 4 cols x 4 rows x K/8 each; K-partials shfl-reduced in-wave.
__global__ __launch_bounds__(512) void scan_kernel(
    const float* __restrict__ Bb, const float* __restrict__ b_x,
    float* __restrict__ ws, float* __restrict__ out)
{
  extern __shared__ float smem[];

  float* xT  = ws + OFF_XT;
  float* sT  = ws + OFF_ST;
  float* zT  = ws + OFF_ZT;
  float* rsT = ws + OFF_RST;
  float* psT = ws + OFF_PST;
  float* suT = ws + OFF_SUT;
  const float* Wt   = ws + OFF_WT;
  const float* Ut1  = ws + OFF_UT1;
  const float* Ust  = ws + OFF_UST;
  const float* Wxot = ws + OFF_WXOT;
  const __hip_bfloat16* hvT = (const __hip_bfloat16*)(ws + OFF_HV);

  const int tid  = threadIdx.x;
  const int bid  = blockIdx.x;
  const int q    = bid & 3;            // batch quadrant
  const int cg   = bid >> 2;           // 0..63 column group
  const int r0   = q * 32;
  const int rq   = tid & 7;            // row-quad: rows 4rq..4rq+3
  const int siw  = (tid >> 3) & 7;     // K-split index (8-lane sub-groups)
  const int wave = tid >> 6;           // 0..7
  const int bq   = r0 + rq * 4;        // base batch row

  unsigned* qbar = (unsigned*)ws + q * 128;

  const bool p1    = (wave < 6);
  const int  c1    = cg * 24 + wave * 4;     // 4-aligned quad, never straddles 512/1024
  const bool fin1  = p1 && (siw == 0);
  const bool p2    = (wave < 4);
  const int  h2    = cg * 8 + wave * 2;
  const bool fin2  = p2 && (siw == 0);
  const bool p3s   = (wave < 4);
  const int  c3    = cg * 16 + wave * 4;
  const bool fin3s = p3s && (siw == 0);
  const bool p3x   = (wave == 4);
  const int  xc    = cg * 4;
  const bool fin3x = p3x && (siw == 0);

  // ---- one-time weight staging into padded LDS layouts ----
  {
    const float4* sW  = (const float4*)(Wt   + (size_t)cg * 6144);
    const float4* sU2 = (const float4*)(Ust  + (size_t)cg * 4096);
    const float4* sU1 = (const float4*)(Ut1  + (size_t)cg * 8192);
    const float4* sWx = (const float4*)(Wxot + (size_t)cg * 2048);
    #pragma unroll
    for (int u = 0; u < 3; ++u) {           // wp1: 24 x 256 -> [24][288]
      int e = u * 512 + tid;                // float4 index
      int c = e >> 6, k4 = e & 63;
      *(float4*)(smem + WP1_OFF + c * 288 + k4 * 4 + (k4 >> 3) * 4) = sW[e];
    }
    #pragma unroll
    for (int u = 0; u < 2; ++u) {           // wp2: 8 x 512 -> [8][544]
      int e = u * 512 + tid;
      int c = e >> 7, k4 = e & 127;
      *(float4*)(smem + WP2_OFF + c * 544 + k4 * 4 + (k4 >> 4) * 4) = sU2[e];
    }
    #pragma unroll
    for (int u = 0; u < 4; ++u) {           // wp3u: 16 x 512 -> [16][544]
      int e = u * 512 + tid;
      int c = e >> 7, k4 = e & 127;
      *(float4*)(smem + WP3U_OFF + c * 544 + k4 * 4 + (k4 >> 4) * 4) = sU1[e];
    }
    {                                       // wp3x: 4 x 512 -> [4][544]
      int e = tid;
      int c = e >> 7, k4 = e & 127;
      *(float4*)(smem + WP3X_OFF + c * 544 + k4 * 4 + (k4 >> 4) * 4) = sWx[e];
    }
  }
  __syncthreads();

  // hoisted per-writer constants
  float bbv[4] = {0.f, 0.f, 0.f, 0.f};
  if (fin1) {
    float4 b4 = *(const float4*)(Bb + c1);
    bbv[0] = b4.x; bbv[1] = b4.y; bbv[2] = b4.z; bbv[3] = b4.w;
  }
  float bxv[4] = {0.f, 0.f, 0.f, 0.f};
  if (fin3x) {
    float4 b4 = *(const float4*)(b_x + xc);
    bxv[0] = b4.x; bxv[1] = b4.y; bxv[2] = b4.z; bxv[3] = b4.w;
  }

  unsigned ep = 0;

  float4 hvv[4];
  #pragma unroll
  for (int cc = 0; cc < 4; ++cc) hvv[cc] = make_float4(0.f, 0.f, 0.f, 0.f);
  if (fin1) {
    #pragma unroll
    for (int cc = 0; cc < 4; ++cc)
      hvv[cc] = ldhv4(hvT + ((size_t)0 * N3 + c1 + cc) * 128 + bq);
  }

  for (int t = 0; t < TSTEPS; ++t) {
    // ================= Phase 1: gates =================
    {
      float4 suv[4], svv[4];
      #pragma unroll
      for (int cc = 0; cc < 4; ++cc) {
        suv[cc] = make_float4(0.f, 0.f, 0.f, 0.f);
        svv[cc] = make_float4(0.f, 0.f, 0.f, 0.f);
      }
      if (fin1) {
        if (c1 < 1024) {
          #pragma unroll
          for (int cc = 0; cc < 4; ++cc)
            suv[cc] = ld4(suT + (size_t)(c1 + cc) * 128 + bq);
        }
        if (c1 < 512) {
          #pragma unroll
          for (int cc = 0; cc < 4; ++cc)
            svv[cc] = ld4(sT + (size_t)(c1 + cc) * 128 + bq);
        }
      }
      stageQ<256>(xT, r0, tid, smem);
      __syncthreads();

      if (p1) {
        float4 acc[4];
        #pragma unroll
        for (int cc = 0; cc < 4; ++cc) acc[cc] = make_float4(0.f, 0.f, 0.f, 0.f);
        const float* sb = smem + (size_t)rq * SSTRIDE + siw * 128;      // k = siw*32..
        const float* wq = smem + WP1_OFF + (size_t)(wave * 4) * 288 + siw * 36;
        dotNC<4, 8>(sb, wq, 288, acc);
        redNC<4>(acc);
        if (fin1) {
          #pragma unroll
          for (int cc = 0; cc < 4; ++cc) {
            float4 pre;
            pre.x = acc[cc].x + hvv[cc].x + bbv[cc] + suv[cc].x;
            pre.y = acc[cc].y + hvv[cc].y + bbv[cc] + suv[cc].y;
            pre.z = acc[cc].z + hvv[cc].z + bbv[cc] + suv[cc].z;
            pre.w = acc[cc].w + hvv[cc].w + bbv[cc] + suv[cc].w;
            if (c1 < 512) {
              float4 r;
              r.x = sigmoid_(pre.x) * svv[cc].x;
              r.y = sigmoid_(pre.y) * svv[cc].y;
              r.z = sigmoid_(pre.z) * svv[cc].z;
              r.w = sigmoid_(pre.w) * svv[cc].w;
              st4(rsT + (size_t)(c1 + cc) * 128 + bq, r);
            } else if (c1 < 1024) {
              float4 zv;
              zv.x = sigmoid_(pre.x); zv.y = sigmoid_(pre.y);
              zv.z = sigmoid_(pre.z); zv.w = sigmoid_(pre.w);
              st4(zT + (size_t)(c1 - 512 + cc) * 128 + bq, zv);
            } else {
              st4(psT + (size_t)(c1 - 1024 + cc) * 128 + bq, pre);
            }
          }
        }
      }
    }
    quad_barrier(qbar, cg, ++ep);

    // ================= Phase 2: state update =================
    {
      if (fin1 && (t + 1 < TSTEPS)) {
        #pragma unroll
        for (int cc = 0; cc < 4; ++cc)
          hvv[cc] = ldhv4(hvT + ((size_t)(t + 1) * N3 + c1 + cc) * 128 + bq);
      }
      float4 psv[2], zvv[2], svv[2];
      #pragma unroll
      for (int cc = 0; cc < 2; ++cc) {
        psv[cc] = make_float4(0.f, 0.f, 0.f, 0.f);
        zvv[cc] = psv[cc]; svv[cc] = psv[cc];
      }
      if (fin2) {
        #pragma unroll
        for (int cc = 0; cc < 2; ++cc) {
          psv[cc] = ld4(psT + (size_t)(h2 + cc) * 128 + bq);
          zvv[cc] = ld4(zT  + (size_t)(h2 + cc) * 128 + bq);
          svv[cc] = ld4(sT  + (size_t)(h2 + cc) * 128 + bq);
        }
      }
      stageQ<512>(rsT, r0, tid, smem);
      __syncthreads();

      if (p2) {
        float4 acc[2];
        acc[0] = make_float4(0.f, 0.f, 0.f, 0.f);
        acc[1] = acc[0];
        const float* sb = smem + (size_t)rq * SSTRIDE + siw * 256;      // k = siw*64..
        const float* wq = smem + WP2_OFF + (size_t)(wave * 2) * 544 + siw * 68;
        dotNC<2, 16>(sb, wq, 544, acc);
        redNC<2>(acc);
        if (fin2) {
          #pragma unroll
          for (int cc = 0; cc < 2; ++cc) {
            float4 s1, sn;
            s1.x = tanh_(psv[cc].x + acc[cc].x);
            s1.y = tanh_(psv[cc].y + acc[cc].y);
            s1.z = tanh_(psv[cc].z + acc[cc].z);
            s1.w = tanh_(psv[cc].w + acc[cc].w);
            sn.x = svv[cc].x + zvv[cc].x * (s1.x - svv[cc].x);
            sn.y = svv[cc].y + zvv[cc].y * (s1.y - svv[cc].y);
            sn.z = svv[cc].z + zvv[cc].z * (s1.z - svv[cc].z);
            sn.w = svv[cc].w + zvv[cc].w * (s1.w - svv[cc].w);
            st4(sT + (size_t)(h2 + cc) * 128 + bq, sn);
          }
        }
      }
    }
    quad_barrier(qbar, cg, ++ep);

    // ================= Phase 3: su lookahead + x_out =================
    {
      stageQ<512>(sT, r0, tid, smem);
      __syncthreads();

      if (p3s) {
        float4 acc[4];
        #pragma unroll
        for (int cc = 0; cc < 4; ++cc) acc[cc] = make_float4(0.f, 0.f, 0.f, 0.f);
        const float* sb = smem + (size_t)rq * SSTRIDE + siw * 256;
        const float* wq = smem + WP3U_OFF + (size_t)(wave * 4) * 544 + siw * 68;
        dotNC<4, 16>(sb, wq, 544, acc);
        redNC<4>(acc);
        if (fin3s) {
          #pragma unroll
          for (int cc = 0; cc < 4; ++cc)
            st4(suT + (size_t)(c3 + cc) * 128 + bq, acc[cc]);
        }
      } else if (p3x) {
        float4 acc[4];
        #pragma unroll
        for (int cc = 0; cc < 4; ++cc) acc[cc] = make_float4(0.f, 0.f, 0.f, 0.f);
        const float* sb = smem + (size_t)rq * SSTRIDE + siw * 256;
        const float* wq = smem + WP3X_OFF + siw * 68;
        dotNC<4, 16>(sb, wq, 544, acc);
        redNC<4>(acc);
        if (fin3x) {
          float4 xv[4];
          #pragma unroll
          for (int cc = 0; cc < 4; ++cc) {
            xv[cc].x = tanh_(acc[cc].x + bxv[cc]);
            xv[cc].y = tanh_(acc[cc].y + bxv[cc]);
            xv[cc].z = tanh_(acc[cc].z + bxv[cc]);
            xv[cc].w = tanh_(acc[cc].w + bxv[cc]);
            st4(xT + (size_t)(xc + cc) * 128 + bq, xv[cc]);
          }
          // out[b][t][xc..xc+3], b = bq..bq+3 (transpose 4x4 in regs)
          stnt4(out + ((size_t)(bq + 0) * TSTEPS + t) * ODIM + xc,
                make_float4(xv[0].x, xv[1].x, xv[2].x, xv[3].x));
          stnt4(out + ((size_t)(bq + 1) * TSTEPS + t) * ODIM + xc,
                make_float4(xv[0].y, xv[1].y, xv[2].y, xv[3].y));
          stnt4(out + ((size_t)(bq + 2) * TSTEPS + t) * ODIM + xc,
                make_float4(xv[0].z, xv[1].z, xv[2].z, xv[3].z));
          stnt4(out + ((size_t)(bq + 3) * TSTEPS + t) * ODIM + xc,
                make_float4(xv[0].w, xv[1].w, xv[2].w, xv[3].w));
        }
      }
    }
    quad_barrier(qbar, cg, ++ep);
  }
}

extern "C" void kernel_launch(void* const* d_in, const int* in_sizes, int n_in,
                              void* d_out, int out_size, void* d_ws, size_t ws_size,
                              hipStream_t stream) {
  const float* H   = (const float*)d_in[0];
  const float* W   = (const float*)d_in[1];
  const float* Bb  = (const float*)d_in[2];
  const float* U   = (const float*)d_in[3];
  const float* W_x = (const float*)d_in[4];
  const float* b_x = (const float*)d_in[5];
  const float* Vr  = (const float*)d_in[6];
  const float* Vz  = (const float*)d_in[7];
  const float* Vs  = (const float*)d_in[8];
  float* out = (float*)d_out;
  float* ws  = (float*)d_ws;
  __hip_bfloat16* hvT = (__hip_bfloat16*)(ws + OFF_HV);

  hipFuncSetAttribute((const void*)scan_kernel,
                      hipFuncAttributeMaxDynamicSharedMemorySize, LDS_BYTES);

  prep_kernel<<<5120, 256, 0, stream>>>(W, U, W_x, ws);
  init_kernel<<<512, 256, 0, stream>>>(H, ws);
  hv_kernel<<<dim3(2048, 24), 256, 0, stream>>>(H, Vr, Vz, Vs, hvT);
  scan_kernel<<<256, 512, LDS_BYTES, stream>>>(Bb, b_x, ws, out);
}